// Round 3
// 629.765 us; speedup vs baseline: 1.0018x; 1.0018x over previous
//
#include <hip/hip_runtime.h>

// BNB 8-bit embedding dequant-on-gather.
// out[t, d] = code[q_idx_flat[x[t]*1024 + d]] * absmax[x[t]>>2]
//
// absmax index: chunk*16 + local/4 = (xv/64)*16 + (xv%64)/4 == xv/4 exactly.
//
// Structure: 2048 grid-stride blocks (8/CU), 256 threads = one token-row per
// iteration (16B int4 load + 4 LDS code lookups + 16B nt-store per thread).
// Depth-2 software pipeline on the q-row gather; x prefetched two iterations
// ahead so the x->q address dependence never stalls the loop.

#define EMBED_DIM 1024

typedef float f32x4 __attribute__((ext_vector_type(4)));  // clang vector: valid for __builtin_nontemporal_store
typedef int   i32x4 __attribute__((ext_vector_type(4)));

__global__ __launch_bounds__(256) void bnb8_embed_kernel(
    const int*   __restrict__ x,
    const int*   __restrict__ q_idx,    // [2000*64*1024] flat
    const float* __restrict__ absmax,   // [2000*16] flat
    const float* __restrict__ code,     // [256]
    float*       __restrict__ out,      // [n_tokens*1024]
    int n_tokens)
{
    __shared__ float code_lds[256];
    const int tid = threadIdx.x;        // 0..255
    code_lds[tid] = code[tid];
    __syncthreads();

    const int stride = gridDim.x;
    const int t0 = blockIdx.x;
    if (t0 >= n_tokens) return;

    // ---- pipeline prologue ----
    // xv one iteration ahead of the q-load, q-load one iteration ahead of use.
    int  xv0 = x[t0];                                  // token t
    const int t1 = t0 + stride;
    int  xv1 = (t1 < n_tokens) ? x[t1] : 0;            // token t+stride

    i32x4 q0 = ((const i32x4*)(q_idx + (size_t)xv0 * EMBED_DIM))[tid];
    float s0 = absmax[xv0 >> 2];

    for (int t = t0; t < n_tokens; ) {
        const int tn  = t + stride;
        const int tnn = tn + stride;

        // issue next q-row gather (address xv1 already resident)
        i32x4 q1 = (i32x4)(0);
        float s1 = 0.0f;
        if (tn < n_tokens) {
            q1 = ((const i32x4*)(q_idx + (size_t)xv1 * EMBED_DIM))[tid];
            s1 = absmax[xv1 >> 2];
        }
        // issue x two iterations ahead
        const int xv2 = (tnn < n_tokens) ? x[tnn] : 0;

        // process current token: 4 LDS lookups + scale, streaming store
        f32x4 v;
        v.x = code_lds[q0.x] * s0;
        v.y = code_lds[q0.y] * s0;
        v.z = code_lds[q0.z] * s0;
        v.w = code_lds[q0.w] * s0;
        __builtin_nontemporal_store(v, (f32x4*)(out + (size_t)t * EMBED_DIM) + tid);

        // shift pipeline
        t   = tn;
        q0  = q1;
        s0  = s1;
        xv1 = xv2;
    }
}

extern "C" void kernel_launch(void* const* d_in, const int* in_sizes, int n_in,
                              void* d_out, int out_size, void* d_ws, size_t ws_size,
                              hipStream_t stream) {
    const int*   x      = (const int*)d_in[0];    // [8*4096]
    const int*   q_idx  = (const int*)d_in[1];    // [2000,64,1024]
    const float* absmax = (const float*)d_in[2];  // [2000,16]
    const float* code   = (const float*)d_in[3];  // [256]
    float*       out    = (float*)d_out;          // [8,4096,1024] fp32

    const int n_tokens = in_sizes[0];             // 32768
    int grid = 2048;                              // 8 blocks/CU * 256 CUs
    if (grid > n_tokens) grid = n_tokens;
    bnb8_embed_kernel<<<grid, 256, 0, stream>>>(x, q_idx, absmax, code, out, n_tokens);
}